// Round 1
// baseline (248.074 us; speedup 1.0000x reference)
//
#include <hip/hip_runtime.h>
#include <hip/hip_bf16.h>
#include <cmath>

// Decoder: 3-layer GRU (B=16, H=2048, E=128) + vocab projection (V=32000) + log_softmax.
// Memory-bound: 516 MB of weights streamed once. Roofline ~82us @ 6.3 TB/s.

#define BB 16
#define HH 2048
#define EE 128
#define VV 32000

__device__ __forceinline__ float sel4(const float a[4], int idx) {
  // static-indexed select (avoid runtime-indexed register array -> scratch)
  float v01 = (idx & 1) ? a[1] : a[0];
  float v23 = (idx & 1) ? a[3] : a[2];
  return (idx & 2) ? v23 : v01;
}

// Accumulate 3 gate rows (j, j+H, j+2H) of W (3H x DIM) against src (B x DIM).
// Wave layout: lane = kk + 16*bg; kk in [0,16) covers k, bg in [0,4) covers 4 batches.
template<int DIM, int CHUNK, bool RELU_EMB>
__device__ __forceinline__
void accum_phase(const float* __restrict__ src, const int* __restrict__ tokens,
                 const float* __restrict__ W, float* sx,
                 int tid, int kk, int bg, int j, float (&acc)[3][4])
{
  constexpr int STR = CHUNK + 4;    // pad 4 floats to stagger LDS banks
  constexpr int F4R = CHUNK / 4;    // float4 per row
  constexpr int NCH = DIM / CHUNK;
  for (int c = 0; c < NCH; ++c) {
    // cooperative load of chunk into LDS (coalesced float4)
    for (int f = tid; f < 16 * F4R; f += 256) {
      int b = f / F4R;
      int i = (f % F4R) * 4;
      float4 v;
      if (RELU_EMB) {
        int tok = tokens[b];
        v = *(const float4*)(src + (size_t)tok * DIM + c * CHUNK + i);
        v.x = fmaxf(v.x, 0.f); v.y = fmaxf(v.y, 0.f);
        v.z = fmaxf(v.z, 0.f); v.w = fmaxf(v.w, 0.f);
      } else {
        v = *(const float4*)(src + (size_t)b * DIM + c * CHUNK + i);
      }
      *(float4*)(sx + b * STR + i) = v;
    }
    __syncthreads();
    #pragma unroll 2
    for (int it = 0; it < CHUNK / 64; ++it) {
      int k = it * 64 + kk * 4;
      float4 xv[4];
      #pragma unroll
      for (int bi = 0; bi < 4; ++bi)
        xv[bi] = *(const float4*)(sx + (bg * 4 + bi) * STR + k);
      #pragma unroll
      for (int g = 0; g < 3; ++g) {
        const float4 wv = *(const float4*)(W + (size_t)(g * HH + j) * DIM + c * CHUNK + k);
        #pragma unroll
        for (int bi = 0; bi < 4; ++bi) {
          acc[g][bi] = fmaf(wv.x, xv[bi].x, acc[g][bi]);
          acc[g][bi] = fmaf(wv.y, xv[bi].y, acc[g][bi]);
          acc[g][bi] = fmaf(wv.z, xv[bi].z, acc[g][bi]);
          acc[g][bi] = fmaf(wv.w, xv[bi].w, acc[g][bi]);
        }
      }
    }
    __syncthreads();
  }
}

// One GRU layer: each wave owns one output column j in [0,2048).
// grid = 512 blocks x 256 threads (4 waves), j = blockIdx*4 + wave.
template<int IN_DIM, bool EMB>
__global__ __launch_bounds__(256, 2)
void gru_kernel(const float* __restrict__ xsrc,   // EMB ? emb(V,E) : x(B,IN_DIM)
                const int* __restrict__ tokens,
                const float* __restrict__ hprev,  // (B,H)
                const float* __restrict__ Wih,    // (3H, IN_DIM)
                const float* __restrict__ Whh,    // (3H, H)
                const float* __restrict__ bih,
                const float* __restrict__ bhh,
                float* __restrict__ hout)         // (B,H)
{
  __shared__ float sx[16 * 516];
  const int tid  = threadIdx.x;
  const int wave = tid >> 6;
  const int lane = tid & 63;
  const int kk   = lane & 15;
  const int bg   = lane >> 4;
  const int j    = blockIdx.x * 4 + wave;

  float accI[3][4] = {};
  float accH[3][4] = {};

  accum_phase<IN_DIM, (IN_DIM == 128 ? 128 : 512), EMB>(xsrc, tokens, Wih, sx, tid, kk, bg, j, accI);
  accum_phase<HH, 512, false>(hprev, nullptr, Whh, sx, tid, kk, bg, j, accH);

  // butterfly reduce across the 16 k-lanes (masks 1,2,4,8 stay within group)
  #pragma unroll
  for (int g = 0; g < 3; ++g) {
    #pragma unroll
    for (int bi = 0; bi < 4; ++bi) {
      float a = accI[g][bi];
      float h = accH[g][bi];
      #pragma unroll
      for (int m = 1; m < 16; m <<= 1) {
        a += __shfl_xor(a, m, 64);
        h += __shfl_xor(h, m, 64);
      }
      accI[g][bi] = a;
      accH[g][bi] = h;
    }
  }

  if (kk < 4) {
    const int b = bg * 4 + kk;
    const float ir = sel4(accI[0], kk) + bih[j];
    const float iz = sel4(accI[1], kk) + bih[j + HH];
    const float in_ = sel4(accI[2], kk) + bih[j + 2 * HH];
    const float hr = sel4(accH[0], kk) + bhh[j];
    const float hz = sel4(accH[1], kk) + bhh[j + HH];
    const float hn = sel4(accH[2], kk) + bhh[j + 2 * HH];
    const float r = 1.f / (1.f + expf(-(ir + hr)));
    const float z = 1.f / (1.f + expf(-(iz + hz)));
    const float n = tanhf(in_ + r * hn);
    const float hp = hprev[(size_t)b * HH + j];
    hout[(size_t)b * HH + j] = (1.f - z) * n + z * hp;
  }
}

// logits[b][v] = h2[b] . W_out[v] + b_out[v]. Each wave owns 4 consecutive v.
// grid = 2000 blocks x 256 threads; block covers 16 v.
__global__ __launch_bounds__(256, 2)
void out_kernel(const float* __restrict__ h2, const float* __restrict__ Wout,
                const float* __restrict__ bout, float* __restrict__ logits)
{
  __shared__ float sx[16 * 516];
  const int tid  = threadIdx.x;
  const int wave = tid >> 6;
  const int lane = tid & 63;
  const int kk   = lane & 15;
  const int bg   = lane >> 4;
  const int vw   = blockIdx.x * 16 + wave * 4;

  float acc[4][4] = {};
  constexpr int CHUNK = 512, STR = 516, F4R = 128;

  for (int c = 0; c < 4; ++c) {
    for (int f = tid; f < 16 * F4R; f += 256) {
      int b = f >> 7;
      int i = (f & 127) * 4;
      *(float4*)(sx + b * STR + i) = *(const float4*)(h2 + (size_t)b * HH + c * CHUNK + i);
    }
    __syncthreads();
    #pragma unroll 2
    for (int it = 0; it < 8; ++it) {
      int k = it * 64 + kk * 4;
      float4 xv[4];
      #pragma unroll
      for (int bi = 0; bi < 4; ++bi)
        xv[bi] = *(const float4*)(sx + (bg * 4 + bi) * STR + k);
      #pragma unroll
      for (int r = 0; r < 4; ++r) {
        const float4 wv = *(const float4*)(Wout + (size_t)(vw + r) * HH + c * CHUNK + k);
        #pragma unroll
        for (int bi = 0; bi < 4; ++bi) {
          acc[r][bi] = fmaf(wv.x, xv[bi].x, acc[r][bi]);
          acc[r][bi] = fmaf(wv.y, xv[bi].y, acc[r][bi]);
          acc[r][bi] = fmaf(wv.z, xv[bi].z, acc[r][bi]);
          acc[r][bi] = fmaf(wv.w, xv[bi].w, acc[r][bi]);
        }
      }
    }
    __syncthreads();
  }

  #pragma unroll
  for (int r = 0; r < 4; ++r) {
    #pragma unroll
    for (int bi = 0; bi < 4; ++bi) {
      float a = acc[r][bi];
      #pragma unroll
      for (int m = 1; m < 16; m <<= 1) a += __shfl_xor(a, m, 64);
      acc[r][bi] = a;
    }
  }

  if (kk < 4) {
    const int b = bg * 4 + kk;
    const float4 bo = *(const float4*)(bout + vw);
    float4 o;
    o.x = sel4(acc[0], kk) + bo.x;
    o.y = sel4(acc[1], kk) + bo.y;
    o.z = sel4(acc[2], kk) + bo.z;
    o.w = sel4(acc[3], kk) + bo.w;
    *(float4*)(logits + (size_t)b * VV + vw) = o;
  }
}

// In-place log_softmax over each row of logits (16 rows x 32000).
__global__ __launch_bounds__(1024)
void lsm_kernel(float* __restrict__ logp)
{
  const int b   = blockIdx.x;
  const int tid = threadIdx.x;
  float* row = logp + (size_t)b * VV;
  const float4* r4 = (const float4*)row;
  __shared__ float red[16];
  const int wv = tid >> 6, ln = tid & 63;

  float m = -3.4e38f;
  for (int i = tid; i < VV / 4; i += 1024) {
    float4 v = r4[i];
    m = fmaxf(m, fmaxf(fmaxf(v.x, v.y), fmaxf(v.z, v.w)));
  }
  #pragma unroll
  for (int s = 1; s < 64; s <<= 1) m = fmaxf(m, __shfl_xor(m, s, 64));
  if (ln == 0) red[wv] = m;
  __syncthreads();
  if (tid == 0) {
    float mm = red[0];
    for (int w = 1; w < 16; ++w) mm = fmaxf(mm, red[w]);
    red[0] = mm;
  }
  __syncthreads();
  const float M = red[0];
  __syncthreads();

  float s = 0.f;
  for (int i = tid; i < VV / 4; i += 1024) {
    float4 v = r4[i];
    s += expf(v.x - M) + expf(v.y - M) + expf(v.z - M) + expf(v.w - M);
  }
  #pragma unroll
  for (int t = 1; t < 64; t <<= 1) s += __shfl_xor(s, t, 64);
  if (ln == 0) red[wv] = s;
  __syncthreads();
  if (tid == 0) {
    float ss = 0.f;
    for (int w = 0; w < 16; ++w) ss += red[w];
    red[0] = M + logf(ss);
  }
  __syncthreads();
  const float L = red[0];

  float4* w4 = (float4*)row;
  for (int i = tid; i < VV / 4; i += 1024) {
    float4 v = r4[i];
    v.x -= L; v.y -= L; v.z -= L; v.w -= L;
    w4[i] = v;
  }
}

extern "C" void kernel_launch(void* const* d_in, const int* in_sizes, int n_in,
                              void* d_out, int out_size, void* d_ws, size_t ws_size,
                              hipStream_t stream)
{
  const int*   tokens = (const int*)d_in[0];   // harness converts integers to int32
  const float* hidden = (const float*)d_in[1]; // (3,B,H)
  const float* emb    = (const float*)d_in[2]; // (V,E)
  const float* Wih0 = (const float*)d_in[3];
  const float* Whh0 = (const float*)d_in[4];
  const float* bih0 = (const float*)d_in[5];
  const float* bhh0 = (const float*)d_in[6];
  const float* Wih1 = (const float*)d_in[7];
  const float* Whh1 = (const float*)d_in[8];
  const float* bih1 = (const float*)d_in[9];
  const float* bhh1 = (const float*)d_in[10];
  const float* Wih2 = (const float*)d_in[11];
  const float* Whh2 = (const float*)d_in[12];
  const float* bih2 = (const float*)d_in[13];
  const float* bhh2 = (const float*)d_in[14];
  const float* Wout = (const float*)d_in[15];
  const float* bout = (const float*)d_in[16];

  float* outp = (float*)d_out;
  float* logp = outp;                       // (B,V) = 512000 floats
  float* hnew = outp + (size_t)BB * VV;     // (3,B,H) = 98304 floats

  gru_kernel<EE, true ><<<512, 256, 0, stream>>>(emb, tokens, hidden,
                                                 Wih0, Whh0, bih0, bhh0, hnew);
  gru_kernel<HH, false><<<512, 256, 0, stream>>>(hnew, nullptr, hidden + BB * HH,
                                                 Wih1, Whh1, bih1, bhh1, hnew + BB * HH);
  gru_kernel<HH, false><<<512, 256, 0, stream>>>(hnew + BB * HH, nullptr, hidden + 2 * BB * HH,
                                                 Wih2, Whh2, bih2, bhh2, hnew + 2 * BB * HH);
  out_kernel<<<2000, 256, 0, stream>>>(hnew + 2 * BB * HH, Wout, bout, logp);
  lsm_kernel<<<16, 1024, 0, stream>>>(logp);
}